// Round 1
// baseline (32.360 us; speedup 1.0000x reference)
//
#include <hip/hip_runtime.h>

// Problem constants (B, S, H) = (8, 2048, 1024), fp32 in/out.
// Math degenerates: attention_scores == 1/S exactly (softmax of a constant
// vector), context[b,h] == mean_s encoder_outputs[b,s,h]. decoder_state_t
// cancels entirely.
#define BB 8
#define SS 2048
#define HH 1024

// Kernel A: partial column sums over S-chunks.
// grid.x = BB * nchunks, block = 256 threads. Thread t owns float4 column
// covering h = 4t..4t+3; each loop iteration the block reads one contiguous
// 4 KB row of encoder_outputs (perfect coalescing).
__global__ void __launch_bounds__(256)
att_partial_kernel(const float* __restrict__ enc, float* __restrict__ partial,
                   int nchunks, int chunk) {
    int blk = blockIdx.x;
    int b = blk / nchunks;
    int c = blk - b * nchunks;
    int t = threadIdx.x;  // 0..255
    const float4* p = (const float4*)(enc + ((size_t)b * SS + (size_t)c * chunk) * HH) + t;
    float4 acc = make_float4(0.f, 0.f, 0.f, 0.f);
    #pragma unroll 8
    for (int s = 0; s < chunk; ++s) {
        float4 v = p[(size_t)s * (HH / 4)];
        acc.x += v.x; acc.y += v.y; acc.z += v.z; acc.w += v.w;
    }
    ((float4*)(partial + ((size_t)b * nchunks + c) * HH))[t] = acc;
}

// Kernel B: reduce partials -> context (first BB*HH floats of d_out), and
// fill attention_scores (next BB*SS floats) with 1/SS.
__global__ void __launch_bounds__(256)
att_finalize_kernel(const float* __restrict__ partial, float* __restrict__ out,
                    int nchunks) {
    int tid = blockIdx.x * blockDim.x + threadIdx.x;
    if (tid < BB * HH) {
        int b = tid / HH;
        int h = tid - b * HH;
        const float* p = partial + (size_t)b * nchunks * HH + h;
        float acc = 0.f;
        for (int c = 0; c < nchunks; ++c) acc += p[(size_t)c * HH];
        out[tid] = acc * (1.0f / SS);
    } else if (tid < BB * HH + BB * SS) {
        out[tid] = 1.0f / SS;
    }
}

// Fallback (no workspace): direct full-column sums, 8192 threads, plus fill.
__global__ void __launch_bounds__(256)
att_direct_kernel(const float* __restrict__ enc, float* __restrict__ out) {
    int tid = blockIdx.x * blockDim.x + threadIdx.x;
    if (tid < BB * HH) {
        int b = tid / HH;
        int h = tid - b * HH;
        const float* p = enc + (size_t)b * SS * HH + h;
        float acc = 0.f;
        for (int s = 0; s < SS; ++s) acc += p[(size_t)s * HH];
        out[tid] = acc * (1.0f / SS);
    } else if (tid < BB * HH + BB * SS) {
        out[tid] = 1.0f / SS;
    }
}

extern "C" void kernel_launch(void* const* d_in, const int* in_sizes, int n_in,
                              void* d_out, int out_size, void* d_ws, size_t ws_size,
                              hipStream_t stream) {
    const float* enc = (const float*)d_in[1];  // encoder_outputs (B,S,H)
    float* out = (float*)d_out;                // [context (B*H) | scores (B*S)]

    const int total_out = BB * HH + BB * SS;   // 24576
    const int fin_blocks = (total_out + 255) / 256;  // 96

    // Pick the largest S-chunk count whose partial buffer fits in d_ws.
    int nchunks = 64;
    while (nchunks > 1 &&
           (size_t)BB * nchunks * HH * sizeof(float) > ws_size)
        nchunks >>= 1;

    if ((size_t)BB * nchunks * HH * sizeof(float) <= ws_size && d_ws != nullptr) {
        int chunk = SS / nchunks;
        float* partial = (float*)d_ws;
        att_partial_kernel<<<BB * nchunks, 256, 0, stream>>>(enc, partial, nchunks, chunk);
        att_finalize_kernel<<<fin_blocks, 256, 0, stream>>>(partial, out, nchunks);
    } else {
        // Workspace too small: slower but correct single-kernel path.
        att_direct_kernel<<<fin_blocks, 256, 0, stream>>>(enc, out);
    }
}

// Round 2
// 23.698 us; speedup vs baseline: 1.3655x; 1.3655x over previous
//
#include <hip/hip_runtime.h>

// (B, S, H) = (8, 2048, 1024), fp32.
// Degenerate math: scores == 1/S exactly (softmax of constant vector);
// context[b,h] == mean_s enc[b,s,h]; decoder_state cancels.
#define BB 8
#define SS 2048
#define HH 1024
#define NCHUNK 128           // S-chunks per batch
#define CHUNK (SS / NCHUNK)  // 16 rows per block

// Kernel A: 1024 blocks (BB*NCHUNK), 256 threads. Thread t owns float4
// column h=4t..4t+3 and loads CHUNK=16 fully-unrolled independent float4s
// (16 loads in flight, 256B/lane) -> pairwise tree sum -> one float4 partial.
__global__ void __launch_bounds__(256)
att_partial_kernel(const float* __restrict__ enc, float* __restrict__ partial) {
    int blk = blockIdx.x;
    int b = blk >> 7;          // / NCHUNK
    int c = blk & (NCHUNK - 1);
    int t = threadIdx.x;
    const float4* p =
        (const float4*)(enc + ((size_t)b * SS + (size_t)c * CHUNK) * HH) + t;
    float4 v[CHUNK];
    #pragma unroll
    for (int s = 0; s < CHUNK; ++s) v[s] = p[(size_t)s * (HH / 4)];
    // pairwise tree reduction (better rounding + no serial dep chain)
    #pragma unroll
    for (int stride = CHUNK / 2; stride > 0; stride >>= 1) {
        #pragma unroll
        for (int s = 0; s < stride; ++s) {
            v[s].x += v[s + stride].x;
            v[s].y += v[s + stride].y;
            v[s].z += v[s + stride].z;
            v[s].w += v[s + stride].w;
        }
    }
    ((float4*)(partial + ((size_t)b * NCHUNK + c) * HH))[t] = v[0];
}

// Kernel B: reduce NCHUNK partials per (b,h) -> context, fill scores with 1/S.
__global__ void __launch_bounds__(256)
att_finalize_kernel(const float* __restrict__ partial, float* __restrict__ out) {
    int tid = blockIdx.x * blockDim.x + threadIdx.x;
    if (tid < BB * HH) {
        int b = tid >> 10;          // / HH
        int h = tid & (HH - 1);
        const float* p = partial + (size_t)b * NCHUNK * HH + h;
        float acc = 0.f;
        #pragma unroll 8
        for (int c = 0; c < NCHUNK; ++c) acc += p[(size_t)c * HH];
        out[tid] = acc * (1.0f / SS);
    } else if (tid < BB * HH + BB * SS) {
        out[tid] = 1.0f / SS;
    }
}

// Fallback (workspace too small): direct full-column sums.
__global__ void __launch_bounds__(256)
att_direct_kernel(const float* __restrict__ enc, float* __restrict__ out) {
    int tid = blockIdx.x * blockDim.x + threadIdx.x;
    if (tid < BB * HH) {
        int b = tid >> 10;
        int h = tid & (HH - 1);
        const float* p = enc + (size_t)b * SS * HH + h;
        float acc = 0.f;
        for (int s = 0; s < SS; ++s) acc += p[(size_t)s * HH];
        out[tid] = acc * (1.0f / SS);
    } else if (tid < BB * HH + BB * SS) {
        out[tid] = 1.0f / SS;
    }
}

extern "C" void kernel_launch(void* const* d_in, const int* in_sizes, int n_in,
                              void* d_out, int out_size, void* d_ws, size_t ws_size,
                              hipStream_t stream) {
    const float* enc = (const float*)d_in[1];  // encoder_outputs (B,S,H)
    float* out = (float*)d_out;                // [context (B*H) | scores (B*S)]

    const int total_out = BB * HH + BB * SS;          // 24576
    const int fin_blocks = (total_out + 255) / 256;   // 96

    const size_t part_bytes = (size_t)BB * NCHUNK * HH * sizeof(float);  // 4 MiB
    if (d_ws != nullptr && ws_size >= part_bytes) {
        float* partial = (float*)d_ws;
        att_partial_kernel<<<BB * NCHUNK, 256, 0, stream>>>(enc, partial);
        att_finalize_kernel<<<fin_blocks, 256, 0, stream>>>(partial, out);
    } else {
        att_direct_kernel<<<fin_blocks, 256, 0, stream>>>(enc, out);
    }
}